// Round 1
// baseline (304.081 us; speedup 1.0000x reference)
//
#include <hip/hip_runtime.h>

// Problem constants (fixed by reference)
#define BB 16
#define SS 1024
#define NIN 7
#define NHID 28
#define NH 7
#define DH 4

constexpr int ROWS = BB * SS;                 // 16384
constexpr int QKV_ELEMS = BB * NH * SS * DH;  // 458752 floats per tensor

// ---------------------------------------------------------------------------
// Kernel 1: QKV projection. inputs [B,S,7] @ W[7,28] + b -> Q,K,V in
// head-major layout [B][H][S][4]. Q pre-scaled by 1/sqrt(DH)=0.5.
// ---------------------------------------------------------------------------
__global__ __launch_bounds__(256) void k_proj(
    const float* __restrict__ inp,
    const float* __restrict__ Wq, const float* __restrict__ bq,
    const float* __restrict__ Wk, const float* __restrict__ bk,
    const float* __restrict__ Wv, const float* __restrict__ bv,
    float* __restrict__ Qo, float* __restrict__ Ko, float* __restrict__ Vo)
{
    __shared__ float  xs[256 * NIN];   // 7 KB: 256 rows of inputs
    __shared__ float4 w4[147];         // Wq(49) | Wk(49) | Wv(49) as float4
    __shared__ float4 b4[21];          // bq(7) | bk(7) | bv(7)

    const int tid  = threadIdx.x;
    const int row0 = blockIdx.x * 256;

    // coalesced stage of this block's 256 input rows
    #pragma unroll
    for (int i = 0; i < NIN; ++i) xs[tid + 256 * i] = inp[row0 * NIN + tid + 256 * i];

    if (tid < 147) {
        const float* src = (tid < 49) ? Wq : (tid < 98) ? Wk : Wv;
        int off = (tid < 49) ? tid : (tid < 98) ? tid - 49 : tid - 98;
        w4[tid] = ((const float4*)src)[off];
    } else if (tid < 168) {
        int t = tid - 147;
        const float* src = (t < 7) ? bq : (t < 14) ? bk : bv;
        b4[t] = ((const float4*)src)[t % 7];
    }
    __syncthreads();

    const int r = row0 + tid;
    const int b = r >> 10, s = r & 1023;

    float x[NIN];
    #pragma unroll
    for (int i = 0; i < NIN; ++i) x[i] = xs[tid * NIN + i];

    float4 q[NH], k[NH], v[NH];
    #pragma unroll
    for (int j4 = 0; j4 < NH; ++j4) { q[j4] = b4[j4]; k[j4] = b4[7 + j4]; v[j4] = b4[14 + j4]; }

    #pragma unroll
    for (int i = 0; i < NIN; ++i) {
        const float xi = x[i];
        #pragma unroll
        for (int j4 = 0; j4 < NH; ++j4) {
            float4 wq = w4[i * 7 + j4];
            float4 wk = w4[49 + i * 7 + j4];
            float4 wv = w4[98 + i * 7 + j4];
            q[j4].x += xi * wq.x; q[j4].y += xi * wq.y; q[j4].z += xi * wq.z; q[j4].w += xi * wq.w;
            k[j4].x += xi * wk.x; k[j4].y += xi * wk.y; k[j4].z += xi * wk.z; k[j4].w += xi * wk.w;
            v[j4].x += xi * wv.x; v[j4].y += xi * wv.y; v[j4].z += xi * wv.z; v[j4].w += xi * wv.w;
        }
    }

    // head h == j4 (since DH==4). Coalesced float4 stores, lanes = consecutive s.
    #pragma unroll
    for (int j4 = 0; j4 < NH; ++j4) {
        const int idx = (b * NH + j4) * SS + s;   // float4 index
        float4 qs = make_float4(0.5f * q[j4].x, 0.5f * q[j4].y, 0.5f * q[j4].z, 0.5f * q[j4].w);
        ((float4*)Qo)[idx] = qs;
        ((float4*)Ko)[idx] = k[j4];
        ((float4*)Vo)[idx] = v[j4];
    }
}

// ---------------------------------------------------------------------------
// Kernel 2: attention 1. One block per (b,h,qtile of 256). K,V for the head in
// LDS (32KB). One thread per query, single-pass softmax (no max-subtraction:
// |score| <~ 30, safe in fp32; softmax is shift-invariant).
// Writes attnOut [B,S,28] (head h -> cols 4h..4h+3).
// ---------------------------------------------------------------------------
__global__ __launch_bounds__(256) void k_attn1(
    const float* __restrict__ Qo, const float* __restrict__ Ko,
    const float* __restrict__ Vo, float* __restrict__ A)
{
    __shared__ float4 Ksh[SS];  // 16 KB
    __shared__ float4 Vsh[SS];  // 16 KB

    const int bh  = blockIdx.x >> 2;
    const int qt  = blockIdx.x & 3;
    const int tid = threadIdx.x;

    const float4* Kg = (const float4*)Ko + (size_t)bh * SS;
    const float4* Vg = (const float4*)Vo + (size_t)bh * SS;
    #pragma unroll
    for (int i = 0; i < 4; ++i) {
        Ksh[tid + 256 * i] = Kg[tid + 256 * i];
        Vsh[tid + 256 * i] = Vg[tid + 256 * i];
    }
    __syncthreads();

    const int q = qt * 256 + tid;
    const float4 qv = ((const float4*)Qo)[(size_t)bh * SS + q];

    float4 acc = make_float4(0.f, 0.f, 0.f, 0.f);
    float l = 0.f;
    #pragma unroll 4
    for (int kk = 0; kk < SS; ++kk) {
        float4 kr = Ksh[kk];                      // broadcast
        float s = qv.x * kr.x + qv.y * kr.y + qv.z * kr.z + qv.w * kr.w;
        float p = __expf(s);
        float4 vr = Vsh[kk];                      // broadcast
        l += p;
        acc.x += p * vr.x; acc.y += p * vr.y; acc.z += p * vr.z; acc.w += p * vr.w;
    }
    const float inv = 1.f / l;
    const int b = bh / NH, h = bh % NH;
    float4 o = make_float4(acc.x * inv, acc.y * inv, acc.z * inv, acc.w * inv);
    ((float4*)A)[(size_t)(b * SS + q) * NH + h] = o;  // 28 floats/row = 7 float4
}

// ---------------------------------------------------------------------------
// Kernel 3: LayerNorm(28) + FFN(28->7)+ReLU+residual -> out (output 0),
// then Q2/K2 projections (7->28). Q2 pre-scaled by 1/sqrt(7).
// One thread per row.
// ---------------------------------------------------------------------------
__global__ __launch_bounds__(256) void k_lnffn(
    const float* __restrict__ A, const float* __restrict__ inp,
    const float* __restrict__ lnw, const float* __restrict__ lnb,
    const float* __restrict__ W1, const float* __restrict__ b1,
    const float* __restrict__ Wq2, const float* __restrict__ bq2,
    const float* __restrict__ Wk2, const float* __restrict__ bk2,
    float* __restrict__ outp, float* __restrict__ Q2, float* __restrict__ K2)
{
    const int r = blockIdx.x * 256 + threadIdx.x;

    float y[NHID];
    const float4* Ar = (const float4*)A + (size_t)r * 7;
    float mu = 0.f;
    #pragma unroll
    for (int j4 = 0; j4 < 7; ++j4) {
        float4 t = Ar[j4];
        y[4 * j4 + 0] = t.x; y[4 * j4 + 1] = t.y; y[4 * j4 + 2] = t.z; y[4 * j4 + 3] = t.w;
        mu += t.x + t.y + t.z + t.w;
    }
    mu *= (1.f / NHID);
    float var = 0.f;
    #pragma unroll
    for (int j = 0; j < NHID; ++j) { float d = y[j] - mu; var += d * d; }
    var *= (1.f / NHID);
    const float rstd = rsqrtf(var + 1e-5f);
    #pragma unroll
    for (int j = 0; j < NHID; ++j) y[j] = (y[j] - mu) * rstd * lnw[j] + lnb[j];

    float o[NIN];
    #pragma unroll
    for (int i = 0; i < NIN; ++i) {
        float a = b1[i];
        #pragma unroll
        for (int j = 0; j < NHID; ++j) a += y[j] * W1[j * NIN + i];
        o[i] = fmaxf(a, 0.f) + inp[r * NIN + i];
        outp[r * NIN + i] = o[i];
    }

    const float rs7 = 0.3779644730092272f;  // 1/sqrt(7)
    float4* Q2r = (float4*)Q2 + (size_t)r * 7;
    float4* K2r = (float4*)K2 + (size_t)r * 7;
    #pragma unroll
    for (int j4 = 0; j4 < 7; ++j4) {
        float qq[4], kk[4];
        #pragma unroll
        for (int c = 0; c < 4; ++c) {
            int j = 4 * j4 + c;
            float aq = bq2[j], ak = bk2[j];
            #pragma unroll
            for (int i = 0; i < NIN; ++i) {
                aq += o[i] * Wq2[i * NHID + j];
                ak += o[i] * Wk2[i * NHID + j];
            }
            qq[c] = aq * rs7; kk[c] = ak;
        }
        Q2r[j4] = make_float4(qq[0], qq[1], qq[2], qq[3]);
        K2r[j4] = make_float4(kk[0], kk[1], kk[2], kk[3]);
    }
}

// ---------------------------------------------------------------------------
// Kernel 4: attention 2 weights. Block = (b, 8-query tile). Each lane holds a
// K2 row (28 VGPRs) reused across the 8 queries; p=exp(s) staged in a 32KB
// LDS tile so exp runs once and the 67MB store is coalesced float4.
// ---------------------------------------------------------------------------
#define QT 8
__global__ __launch_bounds__(256) void k_attn2(
    const float* __restrict__ Q2, const float* __restrict__ K2,
    float* __restrict__ out2)
{
    __shared__ float ptile[QT][SS];      // 32 KB
    __shared__ float q2s[QT * NHID];     // 224 floats
    __shared__ float lsum[QT];

    const int tid = threadIdx.x;
    const int b   = blockIdx.x >> 7;
    const int qt  = blockIdx.x & 127;
    const int q0  = qt * QT;

    if (tid < QT * NHID) q2s[tid] = Q2[(size_t)(b * SS + q0) * NHID + tid];
    if (tid >= 224 && tid < 224 + QT) lsum[tid - 224] = 0.f;
    __syncthreads();

    float lpart[QT];
    #pragma unroll
    for (int qq = 0; qq < QT; ++qq) lpart[qq] = 0.f;

    const float4* K2b = (const float4*)K2 + (size_t)b * SS * 7;
    #pragma unroll
    for (int j = 0; j < 4; ++j) {
        const int k = tid + 256 * j;
        float4 kr[7];
        #pragma unroll
        for (int d4 = 0; d4 < 7; ++d4) kr[d4] = K2b[k * 7 + d4];
        #pragma unroll
        for (int qq = 0; qq < QT; ++qq) {
            const float4* qrow = (const float4*)(q2s + qq * NHID);
            float s = 0.f;
            #pragma unroll
            for (int d4 = 0; d4 < 7; ++d4) {
                float4 qv = qrow[d4];   // LDS broadcast
                s += qv.x * kr[d4].x + qv.y * kr[d4].y + qv.z * kr[d4].z + qv.w * kr[d4].w;
            }
            float p = __expf(s);
            ptile[qq][k] = p;
            lpart[qq] += p;
        }
    }

    const int lane = tid & 63;
    #pragma unroll
    for (int qq = 0; qq < QT; ++qq) {
        float v = lpart[qq];
        #pragma unroll
        for (int off = 32; off > 0; off >>= 1) v += __shfl_down(v, off);
        if (lane == 0) atomicAdd(&lsum[qq], v);
    }
    __syncthreads();

    float* orow = out2 + ((size_t)b * SS + q0) * SS;
    #pragma unroll
    for (int qq = 0; qq < QT; ++qq) {
        float inv = 1.f / lsum[qq];
        float4 pv = ((const float4*)ptile[qq])[tid];
        ((float4*)(orow + (size_t)qq * SS))[tid] =
            make_float4(pv.x * inv, pv.y * inv, pv.z * inv, pv.w * inv);
    }
}

// ---------------------------------------------------------------------------
extern "C" void kernel_launch(void* const* d_in, const int* in_sizes, int n_in,
                              void* d_out, int out_size, void* d_ws, size_t ws_size,
                              hipStream_t stream) {
    const float* inp = (const float*)d_in[0];
    const float* Wq  = (const float*)d_in[1];
    const float* bq  = (const float*)d_in[2];
    const float* Wk  = (const float*)d_in[3];
    const float* bk  = (const float*)d_in[4];
    const float* Wv  = (const float*)d_in[5];
    const float* bv  = (const float*)d_in[6];
    const float* lnw = (const float*)d_in[7];
    const float* lnb = (const float*)d_in[8];
    const float* W1  = (const float*)d_in[9];
    const float* b1  = (const float*)d_in[10];
    const float* Wq2 = (const float*)d_in[11];
    const float* bq2 = (const float*)d_in[12];
    const float* Wk2 = (const float*)d_in[13];
    const float* bk2 = (const float*)d_in[14];

    float* out0 = (float*)d_out;                 // [16,1024,7]
    float* out2 = out0 + ROWS * NIN;             // [16,1024,1024]

    float* ws = (float*)d_ws;
    float* Qo  = ws;
    float* Ko  = ws + (size_t)QKV_ELEMS;
    float* Vo  = ws + (size_t)2 * QKV_ELEMS;
    float* A   = ws + (size_t)3 * QKV_ELEMS;     // [B,S,28] == same elem count
    float* Q2  = ws + (size_t)4 * QKV_ELEMS;
    float* K2  = ws + (size_t)5 * QKV_ELEMS;

    k_proj <<<ROWS / 256, 256, 0, stream>>>(inp, Wq, bq, Wk, bk, Wv, bv, Qo, Ko, Vo);
    k_attn1<<<BB * NH * 4, 256, 0, stream>>>(Qo, Ko, Vo, A);
    k_lnffn<<<ROWS / 256, 256, 0, stream>>>(A, inp, lnw, lnb, W1, b1,
                                            Wq2, bq2, Wk2, bk2, out0, Q2, K2);
    k_attn2<<<BB * (SS / QT), 256, 0, stream>>>(Q2, K2, out2);
}

// Round 2
// 235.966 us; speedup vs baseline: 1.2887x; 1.2887x over previous
//
#include <hip/hip_runtime.h>

// Problem constants (fixed by reference)
#define BB 16
#define SS 1024
#define NIN 7
#define NHID 28
#define NH 7
#define DH 4

constexpr int ROWS = BB * SS;                 // 16384
constexpr int QKV_ELEMS = BB * NH * SS * DH;  // 458752 floats per tensor

// ---------------------------------------------------------------------------
// Kernel 1: QKV projection. inputs [B,S,7] @ W[7,28] + b -> Q,K,V in
// head-major layout [B][H][S][4]. Q pre-scaled by 1/sqrt(DH)=0.5.
// ---------------------------------------------------------------------------
__global__ __launch_bounds__(256) void k_proj(
    const float* __restrict__ inp,
    const float* __restrict__ Wq, const float* __restrict__ bq,
    const float* __restrict__ Wk, const float* __restrict__ bk,
    const float* __restrict__ Wv, const float* __restrict__ bv,
    float* __restrict__ Qo, float* __restrict__ Ko, float* __restrict__ Vo)
{
    __shared__ float  xs[256 * NIN];   // 7 KB: 256 rows of inputs
    __shared__ float4 w4[147];         // Wq(49) | Wk(49) | Wv(49) as float4
    __shared__ float4 b4[21];          // bq(7) | bk(7) | bv(7)

    const int tid  = threadIdx.x;
    const int row0 = blockIdx.x * 256;

    #pragma unroll
    for (int i = 0; i < NIN; ++i) xs[tid + 256 * i] = inp[row0 * NIN + tid + 256 * i];

    if (tid < 147) {
        const float* src = (tid < 49) ? Wq : (tid < 98) ? Wk : Wv;
        int off = (tid < 49) ? tid : (tid < 98) ? tid - 49 : tid - 98;
        w4[tid] = ((const float4*)src)[off];
    } else if (tid < 168) {
        int t = tid - 147;
        const float* src = (t < 7) ? bq : (t < 14) ? bk : bv;
        b4[t] = ((const float4*)src)[t % 7];
    }
    __syncthreads();

    const int r = row0 + tid;
    const int b = r >> 10, s = r & 1023;

    float x[NIN];
    #pragma unroll
    for (int i = 0; i < NIN; ++i) x[i] = xs[tid * NIN + i];

    float4 q[NH], k[NH], v[NH];
    #pragma unroll
    for (int j4 = 0; j4 < NH; ++j4) { q[j4] = b4[j4]; k[j4] = b4[7 + j4]; v[j4] = b4[14 + j4]; }

    #pragma unroll
    for (int i = 0; i < NIN; ++i) {
        const float xi = x[i];
        #pragma unroll
        for (int j4 = 0; j4 < NH; ++j4) {
            float4 wq = w4[i * 7 + j4];
            float4 wk = w4[49 + i * 7 + j4];
            float4 wv = w4[98 + i * 7 + j4];
            q[j4].x += xi * wq.x; q[j4].y += xi * wq.y; q[j4].z += xi * wq.z; q[j4].w += xi * wq.w;
            k[j4].x += xi * wk.x; k[j4].y += xi * wk.y; k[j4].z += xi * wk.z; k[j4].w += xi * wk.w;
            v[j4].x += xi * wv.x; v[j4].y += xi * wv.y; v[j4].z += xi * wv.z; v[j4].w += xi * wv.w;
        }
    }

    #pragma unroll
    for (int j4 = 0; j4 < NH; ++j4) {
        const int idx = (b * NH + j4) * SS + s;   // float4 index
        float4 qs = make_float4(0.5f * q[j4].x, 0.5f * q[j4].y, 0.5f * q[j4].z, 0.5f * q[j4].w);
        ((float4*)Qo)[idx] = qs;
        ((float4*)Ko)[idx] = k[j4];
        ((float4*)Vo)[idx] = v[j4];
    }
}

// ---------------------------------------------------------------------------
// Kernel 2: attention 1. One block per (b,h,qtile of 128), 128 threads.
// 896 blocks -> 3.5 blocks/CU (was 448 -> 1.75, 2:1 tail imbalance).
// K,V for the head in LDS (32KB). One thread per query, single-pass softmax
// (no max-subtraction: |score| bounded, safe in fp32; softmax shift-invariant).
// ---------------------------------------------------------------------------
__global__ __launch_bounds__(128) void k_attn1(
    const float* __restrict__ Qo, const float* __restrict__ Ko,
    const float* __restrict__ Vo, float* __restrict__ A)
{
    __shared__ float4 Ksh[SS];  // 16 KB
    __shared__ float4 Vsh[SS];  // 16 KB

    const int bh  = blockIdx.x >> 3;
    const int qt  = blockIdx.x & 7;
    const int tid = threadIdx.x;

    const float4* Kg = (const float4*)Ko + (size_t)bh * SS;
    const float4* Vg = (const float4*)Vo + (size_t)bh * SS;
    #pragma unroll
    for (int i = 0; i < 8; ++i) {
        Ksh[tid + 128 * i] = Kg[tid + 128 * i];
        Vsh[tid + 128 * i] = Vg[tid + 128 * i];
    }
    __syncthreads();

    const int q = qt * 128 + tid;
    const float4 qv = ((const float4*)Qo)[(size_t)bh * SS + q];

    float4 acc = make_float4(0.f, 0.f, 0.f, 0.f);
    float l = 0.f;
    #pragma unroll 4
    for (int kk = 0; kk < SS; ++kk) {
        float4 kr = Ksh[kk];                      // broadcast (uniform addr)
        float s = qv.x * kr.x + qv.y * kr.y + qv.z * kr.z + qv.w * kr.w;
        float p = __expf(s);
        float4 vr = Vsh[kk];                      // broadcast
        l += p;
        acc.x += p * vr.x; acc.y += p * vr.y; acc.z += p * vr.z; acc.w += p * vr.w;
    }
    const float inv = 1.f / l;
    const int b = bh / NH, h = bh % NH;
    float4 o = make_float4(acc.x * inv, acc.y * inv, acc.z * inv, acc.w * inv);
    ((float4*)A)[(size_t)(b * SS + q) * NH + h] = o;  // 28 floats/row = 7 float4
}

// ---------------------------------------------------------------------------
// Kernel 3: LayerNorm(28) + FFN(28->7)+ReLU+residual -> out (output 0),
// then Q2 (row-major, pre-scaled 1/sqrt(7)) and K2 TRANSPOSED: K2T[b][d][s]
// so k_attn2's per-dim key loads are lane-contiguous. One thread per row.
// ---------------------------------------------------------------------------
__global__ __launch_bounds__(256) void k_lnffn(
    const float* __restrict__ A, const float* __restrict__ inp,
    const float* __restrict__ lnw, const float* __restrict__ lnb,
    const float* __restrict__ W1, const float* __restrict__ b1,
    const float* __restrict__ Wq2, const float* __restrict__ bq2,
    const float* __restrict__ Wk2, const float* __restrict__ bk2,
    float* __restrict__ outp, float* __restrict__ Q2, float* __restrict__ K2T)
{
    const int r = blockIdx.x * 256 + threadIdx.x;

    float y[NHID];
    const float4* Ar = (const float4*)A + (size_t)r * 7;
    float mu = 0.f;
    #pragma unroll
    for (int j4 = 0; j4 < 7; ++j4) {
        float4 t = Ar[j4];
        y[4 * j4 + 0] = t.x; y[4 * j4 + 1] = t.y; y[4 * j4 + 2] = t.z; y[4 * j4 + 3] = t.w;
        mu += t.x + t.y + t.z + t.w;
    }
    mu *= (1.f / NHID);
    float var = 0.f;
    #pragma unroll
    for (int j = 0; j < NHID; ++j) { float d = y[j] - mu; var += d * d; }
    var *= (1.f / NHID);
    const float rstd = rsqrtf(var + 1e-5f);
    #pragma unroll
    for (int j = 0; j < NHID; ++j) y[j] = (y[j] - mu) * rstd * lnw[j] + lnb[j];

    float o[NIN];
    #pragma unroll
    for (int i = 0; i < NIN; ++i) {
        float a = b1[i];
        #pragma unroll
        for (int j = 0; j < NHID; ++j) a += y[j] * W1[j * NIN + i];
        o[i] = fmaxf(a, 0.f) + inp[r * NIN + i];
        outp[r * NIN + i] = o[i];
    }

    const float rs7 = 0.3779644730092272f;  // 1/sqrt(7)
    const int b = r >> 10, s = r & 1023;
    float* K2Tb = K2T + ((size_t)b * NHID) * SS + s;
    float4* Q2r = (float4*)Q2 + (size_t)r * 7;
    #pragma unroll
    for (int j4 = 0; j4 < 7; ++j4) {
        float qq[4];
        #pragma unroll
        for (int c = 0; c < 4; ++c) {
            int j = 4 * j4 + c;
            float aq = bq2[j], ak = bk2[j];
            #pragma unroll
            for (int i = 0; i < NIN; ++i) {
                aq += o[i] * Wq2[i * NHID + j];
                ak += o[i] * Wk2[i * NHID + j];
            }
            qq[c] = aq * rs7;
            K2Tb[(size_t)j * SS] = ak;      // coalesced per-j (lanes = consecutive s)
        }
        Q2r[j4] = make_float4(qq[0], qq[1], qq[2], qq[3]);
    }
}

// ---------------------------------------------------------------------------
// Kernel 4: attention 2 weights. Block = (b, 8-query tile), 256 threads.
// Thread t owns keys 4t..4t+3. K2T loads are lane-contiguous float4 per dim.
// Scores/p stay in registers (s[8][4]); only lsum[8] + q2 staging in LDS.
// exp once per element; final store coalesced float4 per query row.
// ---------------------------------------------------------------------------
#define QT 8
__global__ __launch_bounds__(256) void k_attn2(
    const float* __restrict__ Q2, const float* __restrict__ K2T,
    float* __restrict__ out2)
{
    __shared__ float q2s[QT * NHID];     // 896 B
    __shared__ float lsum[QT];

    const int tid = threadIdx.x;
    const int b   = blockIdx.x >> 7;
    const int qt  = blockIdx.x & 127;
    const int q0  = qt * QT;

    if (tid < QT * NHID) q2s[tid] = Q2[(size_t)(b * SS + q0) * NHID + tid];
    if (tid < QT) lsum[tid] = 0.f;
    __syncthreads();

    const float4* K2b = (const float4*)(K2T + (size_t)b * NHID * SS);  // [28][256] float4

    float s[QT][4];
    #pragma unroll
    for (int qq = 0; qq < QT; ++qq) { s[qq][0] = s[qq][1] = s[qq][2] = s[qq][3] = 0.f; }

    #pragma unroll
    for (int d4 = 0; d4 < 7; ++d4) {
        float4 kt0 = K2b[(d4 * 4 + 0) * (SS / 4) + tid];
        float4 kt1 = K2b[(d4 * 4 + 1) * (SS / 4) + tid];
        float4 kt2 = K2b[(d4 * 4 + 2) * (SS / 4) + tid];
        float4 kt3 = K2b[(d4 * 4 + 3) * (SS / 4) + tid];
        #pragma unroll
        for (int qq = 0; qq < QT; ++qq) {
            float4 qv = ((const float4*)q2s)[qq * 7 + d4];  // broadcast
            s[qq][0] += qv.x * kt0.x + qv.y * kt1.x + qv.z * kt2.x + qv.w * kt3.x;
            s[qq][1] += qv.x * kt0.y + qv.y * kt1.y + qv.z * kt2.y + qv.w * kt3.y;
            s[qq][2] += qv.x * kt0.z + qv.y * kt1.z + qv.z * kt2.z + qv.w * kt3.z;
            s[qq][3] += qv.x * kt0.w + qv.y * kt1.w + qv.z * kt2.w + qv.w * kt3.w;
        }
    }

    const int lane = tid & 63;
    #pragma unroll
    for (int qq = 0; qq < QT; ++qq) {
        s[qq][0] = __expf(s[qq][0]);
        s[qq][1] = __expf(s[qq][1]);
        s[qq][2] = __expf(s[qq][2]);
        s[qq][3] = __expf(s[qq][3]);
        float v = s[qq][0] + s[qq][1] + s[qq][2] + s[qq][3];
        #pragma unroll
        for (int off = 32; off > 0; off >>= 1) v += __shfl_down(v, off);
        if (lane == 0) atomicAdd(&lsum[qq], v);
    }
    __syncthreads();

    float* orow = out2 + ((size_t)b * SS + q0) * SS;
    #pragma unroll
    for (int qq = 0; qq < QT; ++qq) {
        const float iv = 1.f / lsum[qq];
        ((float4*)(orow + (size_t)qq * SS))[tid] =
            make_float4(s[qq][0] * iv, s[qq][1] * iv, s[qq][2] * iv, s[qq][3] * iv);
    }
}

// ---------------------------------------------------------------------------
extern "C" void kernel_launch(void* const* d_in, const int* in_sizes, int n_in,
                              void* d_out, int out_size, void* d_ws, size_t ws_size,
                              hipStream_t stream) {
    const float* inp = (const float*)d_in[0];
    const float* Wq  = (const float*)d_in[1];
    const float* bq  = (const float*)d_in[2];
    const float* Wk  = (const float*)d_in[3];
    const float* bk  = (const float*)d_in[4];
    const float* Wv  = (const float*)d_in[5];
    const float* bv  = (const float*)d_in[6];
    const float* lnw = (const float*)d_in[7];
    const float* lnb = (const float*)d_in[8];
    const float* W1  = (const float*)d_in[9];
    const float* b1  = (const float*)d_in[10];
    const float* Wq2 = (const float*)d_in[11];
    const float* bq2 = (const float*)d_in[12];
    const float* Wk2 = (const float*)d_in[13];
    const float* bk2 = (const float*)d_in[14];

    float* out0 = (float*)d_out;                 // [16,1024,7]
    float* out2 = out0 + ROWS * NIN;             // [16,1024,1024]

    float* ws = (float*)d_ws;
    float* Qo  = ws;
    float* Ko  = ws + (size_t)QKV_ELEMS;
    float* Vo  = ws + (size_t)2 * QKV_ELEMS;
    float* A   = ws + (size_t)3 * QKV_ELEMS;     // [B,S,28] == same elem count
    float* Q2  = ws + (size_t)4 * QKV_ELEMS;
    float* K2T = ws + (size_t)5 * QKV_ELEMS;     // [B,28,S]

    k_proj <<<ROWS / 256, 256, 0, stream>>>(inp, Wq, bq, Wk, bk, Wv, bv, Qo, Ko, Vo);
    k_attn1<<<BB * NH * 8, 128, 0, stream>>>(Qo, Ko, Vo, A);
    k_lnffn<<<ROWS / 256, 256, 0, stream>>>(A, inp, lnw, lnb, W1, b1,
                                            Wq2, bq2, Wk2, bk2, out0, Q2, K2T);
    k_attn2<<<BB * (SS / QT), 256, 0, stream>>>(Q2, K2T, out2);
}